// Round 17
// baseline (350.969 us; speedup 1.0000x reference)
//
#include <hip/hip_runtime.h>

using f16   = _Float16;
using f16x4 = __attribute__((ext_vector_type(4))) _Float16;
using f16x8 = __attribute__((ext_vector_type(8))) _Float16;
using f32x4 = __attribute__((ext_vector_type(4))) float;

#define DEVI __device__ __forceinline__

namespace {
// 32KB LDS, ONE barrier per block:
//  S_O  @0   : shared O [64][128] f16 swzA (written pre-barrier, read post)
//  S_SCR @16K: 4KB per-wave scratch, time-multiplexed (wave-private order):
//              Q [64][32] -> K -> P k-halves x2 -> V^T [32][64]
// X tiles are never staged: Q/K/V A-fragments read straight from global fp32
// (the block's 4 waves read the same tile -> L1/L2 serve the re-reads).
constexpr int S_O   = 0;
constexpr int S_SCR = 16384;
constexpr float LOGIT_MAX_C = 4.6051701859880914f;  // log(100)
constexpr float L2E = 1.4426950408889634f;
}

// XOR swizzles. Masks only touch bits >=4 so 8/16B-aligned vector accesses stay
// block-aligned with byte order preserved (bit-3 masks corrupt — R8 lesson).
DEVI int swzA(int row, int b) { return (row << 8) + (b ^ ((row & 7) << 4)); }   // 256B rows
DEVI int swz64(int row, int b) { return (row << 6) + (b ^ (((row >> 1) & 3) << 4)); }  // 64B rows

DEVI f16x8 ldA(const char* base, int row, int k0) {   // [*,128] f16 tile, b128
  return *reinterpret_cast<const f16x8*>(base + swzA(row, k0 << 1));
}

// 8 consecutive fp32 from a [*,128] row-major global matrix -> f16x8.
DEVI f16x8 ld_g8(const float* __restrict__ G, int row, int k0) {
  const float4* p = reinterpret_cast<const float4*>(G + row * 128 + k0);
  float4 a = p[0], c = p[1];
  f16x8 r;
  r[0] = (f16)a.x; r[1] = (f16)a.y; r[2] = (f16)a.z; r[3] = (f16)a.w;
  r[4] = (f16)c.x; r[5] = (f16)c.y; r[6] = (f16)c.z; r[7] = (f16)c.w;
  return r;
}

// X(global fp32) @ W^T accumulate (W fragments from L2-resident f16 table).
DEVI void projG_acc(const float* __restrict__ X, const f16* __restrict__ Wm,
                    f32x4 (&acc)[4][2], int w, int lr, int lg) {
#pragma unroll
  for (int mt = 0; mt < 4; ++mt)
#pragma unroll
    for (int n = 0; n < 2; ++n)
      acc[mt][n] = f32x4{0.f, 0.f, 0.f, 0.f};
#pragma unroll
  for (int kt = 0; kt < 4; ++kt) {
    f16x8 b0 = *reinterpret_cast<const f16x8*>(Wm + (w * 32 + lr) * 128 + kt * 32 + lg * 8);
    f16x8 b1 = *reinterpret_cast<const f16x8*>(Wm + (w * 32 + 16 + lr) * 128 + kt * 32 + lg * 8);
#pragma unroll
    for (int mt = 0; mt < 4; ++mt) {
      f16x8 a = ld_g8(X, mt * 16 + lr, kt * 32 + lg * 8);
      acc[mt][0] = __builtin_amdgcn_mfma_f32_16x16x32_f16(a, b0, acc[mt][0], 0, 0, 0);
      acc[mt][1] = __builtin_amdgcn_mfma_f32_16x16x32_f16(a, b1, acc[mt][1], 0, 0, 0);
    }
  }
}

// X(lds f16) @ W^T accumulate — used only for the final x projection.
DEVI void proj_acc(const char* __restrict__ xb, const f16* __restrict__ Wm,
                   f32x4 (&acc)[4][2], int w, int lr, int lg) {
#pragma unroll
  for (int mt = 0; mt < 4; ++mt)
#pragma unroll
    for (int n = 0; n < 2; ++n)
      acc[mt][n] = f32x4{0.f, 0.f, 0.f, 0.f};
#pragma unroll
  for (int kt = 0; kt < 4; ++kt) {
    f16x8 b0 = *reinterpret_cast<const f16x8*>(Wm + (w * 32 + lr) * 128 + kt * 32 + lg * 8);
    f16x8 b1 = *reinterpret_cast<const f16x8*>(Wm + (w * 32 + 16 + lr) * 128 + kt * 32 + lg * 8);
#pragma unroll
    for (int mt = 0; mt < 4; ++mt) {
      f16x8 a = ldA(xb, mt * 16 + lr, kt * 32 + lg * 8);
      acc[mt][0] = __builtin_amdgcn_mfma_f32_16x16x32_f16(a, b0, acc[mt][0], 0, 0, 0);
      acc[mt][1] = __builtin_amdgcn_mfma_f32_16x16x32_f16(a, b1, acc[mt][1], 0, 0, 0);
    }
  }
}

// C/D -> wave-private [64 rows][32 cols] f16 scratch (64B rows, swz64).
DEVI void epi_scr64(const f32x4 (&acc)[4][2], char* __restrict__ scr,
                    const float* __restrict__ bias, int lr, int lg) {
  float b0 = bias ? bias[lr] : 0.f;
  float b1 = bias ? bias[16 + lr] : 0.f;
#pragma unroll
  for (int mt = 0; mt < 4; ++mt)
#pragma unroll
    for (int n = 0; n < 2; ++n)
#pragma unroll
      for (int r = 0; r < 4; ++r) {
        int row = mt * 16 + lg * 4 + r;
        *reinterpret_cast<f16*>(scr + swz64(row, (n * 16 + lr) << 1)) =
            (f16)(acc[mt][n][r] + (n ? b1 : b0));
      }
}
// fragment read from 64B-row scratch: row-major, features lg*8..+8 (16B)
DEVI f16x8 ldS64(const char* __restrict__ scr, int row, int lg) {
  return *reinterpret_cast<const f16x8*>(scr + swz64(row, lg << 4));
}

// C/D (col=lane&15, row=(lane>>4)*4+r) -> shared row-major [64][128] f16, own cols.
DEVI void epi_rowmajor(const f32x4 (&acc)[4][2], char* __restrict__ dst,
                       int w, int lr, int lg) {
#pragma unroll
  for (int mt = 0; mt < 4; ++mt)
#pragma unroll
    for (int n = 0; n < 2; ++n)
#pragma unroll
      for (int r = 0; r < 4; ++r) {
        int row = mt * 16 + lg * 4 + r;
        int col = w * 32 + n * 16 + lr;
        *reinterpret_cast<f16*>(dst + swzA(row, col << 1)) = (f16)acc[mt][n][r];
      }
}

// fp32 weights -> f16 workspace (Wq,Wk,Wv,Wp)
__global__ void wcvt_kernel(const float* __restrict__ Wq, const float* __restrict__ Wk,
                            const float* __restrict__ Wv, const float* __restrict__ Wp,
                            f16* __restrict__ W16) {
  int idx = blockIdx.x * 256 + threadIdx.x;   // 0..16383
  int m = idx >> 12;
  int off = (idx & 4095) << 2;
  const float* src = m == 0 ? Wq : m == 1 ? Wk : m == 2 ? Wv : Wp;
  float4 v = *reinterpret_cast<const float4*>(src + off);
  f16x4 h;
  h[0] = (f16)v.x; h[1] = (f16)v.y; h[2] = (f16)v.z; h[3] = (f16)v.w;
  *reinterpret_cast<f16x4*>(W16 + (m << 14) + off) = h;
}

__global__ __launch_bounds__(256, 4)
void fpca_kernel(const float* __restrict__ q_in, const float* __restrict__ k_in,
                 const float* __restrict__ v_in, const float* __restrict__ pos_in,
                 const f16* __restrict__ W16,
                 const float* __restrict__ bq, const float* __restrict__ bv,
                 const float* __restrict__ bp, const float* __restrict__ lsc,
                 float* __restrict__ d_x, float* __restrict__ d_attn) {
  __shared__ char smem[32768];
  const int tid = threadIdx.x;
  const int w = tid >> 6;        // wave id == head id
  const int lane = tid & 63;
  const int lr = lane & 15;
  const int lg = lane >> 4;
  const int win = blockIdx.x;
  const int b = win >> 8;
  const size_t winOff = (size_t)win << 13;
  const f16* Wq16 = W16;
  const f16* Wk16 = W16 + 16384;
  const f16* Wv16 = W16 + 32768;
  const f16* Wp16 = W16 + 49152;
  char* scr = smem + S_SCR + (w << 12);   // 4KB wave-private scratch

  // ================= wave-private free-running section =================
  // ---- Q projection (global X) -> scr -> bQ ----
  f32x4 acc[4][2];
  projG_acc(q_in + winOff, Wq16, acc, w, lr, lg);
  epi_scr64(acc, scr, bq + w * 32, lr, lg);
  f16x8 bQ[4];
#pragma unroll
  for (int nt = 0; nt < 4; ++nt) bQ[nt] = ldS64(scr, nt * 16 + lr, lg);

  // ---- K projection (global X) -> scr (Q dead) -> aK ----
  projG_acc(k_in + winOff, Wk16, acc, w, lr, lg);
  epi_scr64(acc, scr, nullptr, lr, lg);
  f16x8 aK[4];
#pragma unroll
  for (int mt = 0; mt < 4; ++mt) aK[mt] = ldS64(scr, mt * 16 + lr, lg);

  // ---- S^T = K Q^T + scale/pos, softmax per q-col, attn out, P16 pack ----
  const float scale = exp2f(fminf(lsc[w], LOGIT_MAX_C) * L2E);
  const float* pos = pos_in + (((size_t)b * 4 + w) << 12);
  float* attn_out = d_attn + (((size_t)win * 4 + w) << 12);
  f16x4 P16[4][4];   // P16[mt][nt]: q=nt*16+lr, k=mt*16+lg*4+r
#pragma unroll
  for (int nt = 0; nt < 4; ++nt) {
    f32x4 s[4];
#pragma unroll
    for (int mt = 0; mt < 4; ++mt) s[mt] = f32x4{0.f, 0.f, 0.f, 0.f};
#pragma unroll
    for (int mt = 0; mt < 4; ++mt)
      s[mt] = __builtin_amdgcn_mfma_f32_16x16x32_f16(aK[mt], bQ[nt], s[mt], 0, 0, 0);
    const int q = nt * 16 + lr;   // lane's q-col; k = mt*16+lg*4+r (lane-local)
#pragma unroll
    for (int mt = 0; mt < 4; ++mt) {
      float4 pv = *reinterpret_cast<const float4*>(pos + (q << 6) + mt * 16 + lg * 4);
      s[mt][0] = s[mt][0] * scale + pv.x;
      s[mt][1] = s[mt][1] * scale + pv.y;
      s[mt][2] = s[mt][2] * scale + pv.z;
      s[mt][3] = s[mt][3] * scale + pv.w;
    }
    float m = s[0][0];
#pragma unroll
    for (int mt = 0; mt < 4; ++mt)
#pragma unroll
      for (int r = 0; r < 4; ++r) m = fmaxf(m, s[mt][r]);
    m = fmaxf(m, __shfl_xor(m, 16));
    m = fmaxf(m, __shfl_xor(m, 32));
    float sum = 0.f;
#pragma unroll
    for (int mt = 0; mt < 4; ++mt)
#pragma unroll
      for (int r = 0; r < 4; ++r) {
        float e = exp2f((s[mt][r] - m) * L2E);
        s[mt][r] = e;
        sum += e;
      }
    sum += __shfl_xor(sum, 16);
    sum += __shfl_xor(sum, 32);
    float rinv = __builtin_amdgcn_rcpf(sum);
#pragma unroll
    for (int mt = 0; mt < 4; ++mt) {
      float4 o;
      o.x = (s[mt][0] *= rinv);
      o.y = (s[mt][1] *= rinv);
      o.z = (s[mt][2] *= rinv);
      o.w = (s[mt][3] *= rinv);
      *reinterpret_cast<float4*>(attn_out + (q << 6) + mt * 16 + lg * 4) = o;
      P16[mt][nt][0] = (f16)s[mt][0];
      P16[mt][nt][1] = (f16)s[mt][1];
      P16[mt][nt][2] = (f16)s[mt][2];
      P16[mt][nt][3] = (f16)s[mt][3];
    }
  }

  // ---- P k-halves -> scr [64 q][32 k] (time-shared, K dead) -> aP hoist ----
#define WR_P(MT)                                                                   \
  {                                                                                \
    _Pragma("unroll") for (int nt = 0; nt < 4; ++nt) {                             \
      const int q = nt * 16 + lr;                                                  \
      *reinterpret_cast<f16x4*>(scr + (q << 6) +                                   \
          (((((MT) & 1) << 5) + (lg << 3)) ^ (((q >> 1) & 3) << 4))) =             \
          P16[MT][nt];                                                             \
    }                                                                              \
  }
  f16x8 aP[4][2];
#pragma unroll
  for (int h = 0; h < 2; ++h) {
    WR_P(2 * h)
    WR_P(2 * h + 1)
#pragma unroll
    for (int mt = 0; mt < 4; ++mt) {
      const int q = mt * 16 + lr;
      aP[mt][h] = *reinterpret_cast<const f16x8*>(scr + (q << 6) +
          ((lg << 4) ^ (((q >> 1) & 3) << 4)));
    }
  }
#undef WR_P

  // ---- V projection (global X) -> V^T scr [32][64] (P dead) -> bV ----
  projG_acc(v_in + winOff, Wv16, acc, w, lr, lg);
  {
    float c0 = bv[w * 32 + lr], c1 = bv[w * 32 + 16 + lr];
#pragma unroll
    for (int mt = 0; mt < 4; ++mt)
#pragma unroll
      for (int n = 0; n < 2; ++n) {
        int d = n * 16 + lr;                 // local feature row of V^T [32][64]
        f16x4 h;
        h[0] = (f16)(acc[mt][n][0] + (n ? c1 : c0));
        h[1] = (f16)(acc[mt][n][1] + (n ? c1 : c0));
        h[2] = (f16)(acc[mt][n][2] + (n ? c1 : c0));
        h[3] = (f16)(acc[mt][n][3] + (n ? c1 : c0));
        *reinterpret_cast<f16x4*>(scr + (d << 7) +
            ((mt * 32 + lg * 8) ^ ((d & 7) << 4))) = h;
      }
  }
  f16x8 bV[2][2];
#pragma unroll
  for (int n = 0; n < 2; ++n)
#pragma unroll
    for (int kt = 0; kt < 2; ++kt) {
      int d = n * 16 + lr;
      bV[n][kt] = *reinterpret_cast<const f16x8*>(scr + (d << 7) +
          ((kt * 64 + lg * 16) ^ ((d & 7) << 4)));
    }

  // ---- O_h = P @ V_h ----
  f32x4 oacc[4][2];
#pragma unroll
  for (int mt = 0; mt < 4; ++mt)
#pragma unroll
    for (int n = 0; n < 2; ++n)
      oacc[mt][n] = f32x4{0.f, 0.f, 0.f, 0.f};
#pragma unroll
  for (int mt = 0; mt < 4; ++mt)
#pragma unroll
    for (int kt = 0; kt < 2; ++kt) {
      oacc[mt][0] = __builtin_amdgcn_mfma_f32_16x16x32_f16(aP[mt][kt], bV[0][kt], oacc[mt][0], 0, 0, 0);
      oacc[mt][1] = __builtin_amdgcn_mfma_f32_16x16x32_f16(aP[mt][kt], bV[1][kt], oacc[mt][1], 0, 0, 0);
    }

  // ---- O (merged heads) -> shared S_O, own cols ----
  epi_rowmajor(oacc, smem + S_O, w, lr, lg);
  // ================= end wave-private section =================
  __syncthreads();  // the ONLY barrier: all 4 heads' O columns written

  // ---- x = O @ Wp^T + bp -> global fp32 ----
  f32x4 xacc[4][2];
  proj_acc(smem + S_O, Wp16, xacc, w, lr, lg);
  const float b0 = bp[w * 32 + lr];
  const float b1 = bp[w * 32 + 16 + lr];
  float* xo = d_x + winOff;
#pragma unroll
  for (int mt = 0; mt < 4; ++mt)
#pragma unroll
    for (int n = 0; n < 2; ++n)
#pragma unroll
      for (int r = 0; r < 4; ++r) {
        int row = mt * 16 + lg * 4 + r;
        int col = w * 32 + n * 16 + lr;
        xo[(row << 7) + col] = xacc[mt][n][r] + (n ? b1 : b0);
      }
}

extern "C" void kernel_launch(void* const* d_in, const int* in_sizes, int n_in,
                              void* d_out, int out_size, void* d_ws, size_t ws_size,
                              hipStream_t stream) {
  const float* q   = (const float*)d_in[0];
  const float* k   = (const float*)d_in[1];
  const float* v   = (const float*)d_in[2];
  const float* pos = (const float*)d_in[3];
  const float* Wq  = (const float*)d_in[4];
  const float* bq  = (const float*)d_in[5];
  const float* Wk  = (const float*)d_in[6];
  const float* Wv  = (const float*)d_in[7];
  const float* bv  = (const float*)d_in[8];
  const float* Wp  = (const float*)d_in[9];
  const float* bp  = (const float*)d_in[10];
  const float* ls  = (const float*)d_in[11];
  f16* W16 = (f16*)d_ws;   // 4 x 128 x 128 f16 = 128KB
  float* d_x    = (float*)d_out;
  float* d_attn = d_x + (size_t)16 * 16 * 16 * 64 * 128;  // 33,554,432
  wcvt_kernel<<<64, 256, 0, stream>>>(Wq, Wk, Wv, Wp, W16);
  fpca_kernel<<<4096, 256, 0, stream>>>(q, k, v, pos, W16, bq, bv, bp, ls,
                                        d_x, d_attn);
}

// Round 18
// 205.705 us; speedup vs baseline: 1.7062x; 1.7062x over previous
//
#include <hip/hip_runtime.h>

using f16   = _Float16;
using f16x4 = __attribute__((ext_vector_type(4))) _Float16;
using f16x8 = __attribute__((ext_vector_type(8))) _Float16;
using f32x4 = __attribute__((ext_vector_type(4))) float;

#define DEVI __device__ __forceinline__

namespace {
// 48KB LDS:
//  S_XQ @0    : Xq [64][128] f16 swzA -> (dead after BAR2) P k-half1 chunks
//               (4KB/wave) -> O [64][128] (own cols, after BAR3)
//  S_XK @16K  : Xk [64][128] f16 swzA -> Xv (regs->LDS after BAR2)
//  S_SCR @32K : 4KB per-wave scratch: Q -> K -> P k-half0 -> V^T [32][64]
constexpr int S_XQ  = 0;
constexpr int S_XK  = 16384;
constexpr int S_SCR = 32768;
constexpr float LOGIT_MAX_C = 4.6051701859880914f;  // log(100)
constexpr float L2E = 1.4426950408889634f;
}

// XOR swizzles. Masks only touch bits >=4 so 8/16B-aligned vector accesses stay
// block-aligned with byte order preserved (bit-3 masks corrupt — R8 lesson).
DEVI int swzA(int row, int b) { return (row << 8) + (b ^ ((row & 7) << 4)); }   // 256B rows
DEVI int swz64(int row, int b) { return (row << 6) + (b ^ (((row >> 1) & 3) << 4)); }  // 64B rows

DEVI f16x8 ldA(const char* base, int row, int k0) {   // [*,128] f16 tile, b128
  return *reinterpret_cast<const f16x8*>(base + swzA(row, k0 << 1));
}

// Stage one 64x128 fp32 tile -> f16 swizzled LDS tile (coalesced float4 loads)
DEVI void stage_in(const float* __restrict__ src, char* __restrict__ dst, int tid) {
#pragma unroll
  for (int i = 0; i < 8; ++i) {
    int f = tid + (i << 8);
    float4 v = reinterpret_cast<const float4*>(src)[f];
    f16x4 h;
    h[0] = (f16)v.x; h[1] = (f16)v.y; h[2] = (f16)v.z; h[3] = (f16)v.w;
    *reinterpret_cast<f16x4*>(dst + swzA(f >> 5, (f & 31) << 3)) = h;
  }
}

// X(lds) @ W^T accumulate (W fragments loaded per-kt from L2-resident f16 table).
DEVI void proj_acc(const char* __restrict__ xb, const f16* __restrict__ Wm,
                   f32x4 (&acc)[4][2], int w, int lr, int lg) {
#pragma unroll
  for (int mt = 0; mt < 4; ++mt)
#pragma unroll
    for (int n = 0; n < 2; ++n)
      acc[mt][n] = f32x4{0.f, 0.f, 0.f, 0.f};
#pragma unroll
  for (int kt = 0; kt < 4; ++kt) {
    f16x8 b0 = *reinterpret_cast<const f16x8*>(Wm + (w * 32 + lr) * 128 + kt * 32 + lg * 8);
    f16x8 b1 = *reinterpret_cast<const f16x8*>(Wm + (w * 32 + 16 + lr) * 128 + kt * 32 + lg * 8);
#pragma unroll
    for (int mt = 0; mt < 4; ++mt) {
      f16x8 a = ldA(xb, mt * 16 + lr, kt * 32 + lg * 8);
      acc[mt][0] = __builtin_amdgcn_mfma_f32_16x16x32_f16(a, b0, acc[mt][0], 0, 0, 0);
      acc[mt][1] = __builtin_amdgcn_mfma_f32_16x16x32_f16(a, b1, acc[mt][1], 0, 0, 0);
    }
  }
}

// C/D -> wave-private [64 rows][32 cols] f16 scratch (64B rows, swz64).
DEVI void epi_scr64(const f32x4 (&acc)[4][2], char* __restrict__ scr,
                    const float* __restrict__ bias, int lr, int lg) {
  float b0 = bias ? bias[lr] : 0.f;
  float b1 = bias ? bias[16 + lr] : 0.f;
#pragma unroll
  for (int mt = 0; mt < 4; ++mt)
#pragma unroll
    for (int n = 0; n < 2; ++n)
#pragma unroll
      for (int r = 0; r < 4; ++r) {
        int row = mt * 16 + lg * 4 + r;
        *reinterpret_cast<f16*>(scr + swz64(row, (n * 16 + lr) << 1)) =
            (f16)(acc[mt][n][r] + (n ? b1 : b0));
      }
}
// fragment read from 64B-row scratch: row-major, features lg*8..+8 (16B)
DEVI f16x8 ldS64(const char* __restrict__ scr, int row, int lg) {
  return *reinterpret_cast<const f16x8*>(scr + swz64(row, lg << 4));
}

// C/D (col=lane&15, row=(lane>>4)*4+r) -> shared row-major [64][128] f16, own cols.
DEVI void epi_rowmajor(const f32x4 (&acc)[4][2], char* __restrict__ dst,
                       int w, int lr, int lg) {
#pragma unroll
  for (int mt = 0; mt < 4; ++mt)
#pragma unroll
    for (int n = 0; n < 2; ++n)
#pragma unroll
      for (int r = 0; r < 4; ++r) {
        int row = mt * 16 + lg * 4 + r;
        int col = w * 32 + n * 16 + lr;
        *reinterpret_cast<f16*>(dst + swzA(row, col << 1)) = (f16)acc[mt][n][r];
      }
}

// fp32 weights -> f16 workspace (Wq,Wk,Wv,Wp)
__global__ void wcvt_kernel(const float* __restrict__ Wq, const float* __restrict__ Wk,
                            const float* __restrict__ Wv, const float* __restrict__ Wp,
                            f16* __restrict__ W16) {
  int idx = blockIdx.x * 256 + threadIdx.x;   // 0..16383
  int m = idx >> 12;
  int off = (idx & 4095) << 2;
  const float* src = m == 0 ? Wq : m == 1 ? Wk : m == 2 ? Wv : Wp;
  float4 v = *reinterpret_cast<const float4*>(src + off);
  f16x4 h;
  h[0] = (f16)v.x; h[1] = (f16)v.y; h[2] = (f16)v.z; h[3] = (f16)v.w;
  *reinterpret_cast<f16x4*>(W16 + (m << 14) + off) = h;
}

__global__ __launch_bounds__(256, 3)
void fpca_kernel(const float* __restrict__ q_in, const float* __restrict__ k_in,
                 const float* __restrict__ v_in, const float* __restrict__ pos_in,
                 const f16* __restrict__ W16,
                 const float* __restrict__ bq, const float* __restrict__ bv,
                 const float* __restrict__ bp, const float* __restrict__ lsc,
                 float* __restrict__ d_x, float* __restrict__ d_attn) {
  __shared__ char smem[49152];
  const int tid = threadIdx.x;
  const int w = tid >> 6;        // wave id == head id
  const int lane = tid & 63;
  const int lr = lane & 15;
  const int lg = lane >> 4;
  const int win = blockIdx.x;
  const int b = win >> 8;
  const size_t winOff = (size_t)win << 13;
  const f16* Wq16 = W16;
  const f16* Wk16 = W16 + 16384;
  const f16* Wv16 = W16 + 32768;
  const f16* Wp16 = W16 + 49152;
  char* scr = smem + S_SCR + (w << 12);       // 4KB wave-private scratch
  char* Ph1 = smem + S_XQ + (w << 12);        // P k-half1 chunk (S_XQ dead post-BAR2)

  // ---- ph1: stage Xq->S_XQ, Xk->S_XK; prefetch Xv into f16 regs ----
  stage_in(q_in + winOff, smem + S_XQ, tid);
  stage_in(k_in + winOff, smem + S_XK, tid);
  const float4* vsrc = reinterpret_cast<const float4*>(v_in + winOff);
  f16x4 pfh[8];
#pragma unroll
  for (int i = 0; i < 8; ++i) {
    float4 v = vsrc[tid + (i << 8)];
    pfh[i][0] = (f16)v.x; pfh[i][1] = (f16)v.y;
    pfh[i][2] = (f16)v.z; pfh[i][3] = (f16)v.w;
  }
  __syncthreads();  // BAR1: stage regions valid

  // ---- Q proj; epi Q; K proj (covers Q round trip); bQ; epi K; aK ----
  f32x4 acc[4][2];
  proj_acc(smem + S_XQ, Wq16, acc, w, lr, lg);
  epi_scr64(acc, scr, bq + w * 32, lr, lg);
  proj_acc(smem + S_XK, Wk16, acc, w, lr, lg);   // K MFMAs hide Q write->read
  f16x8 bQ[4];
#pragma unroll
  for (int nt = 0; nt < 4; ++nt) bQ[nt] = ldS64(scr, nt * 16 + lr, lg);
  epi_scr64(acc, scr, nullptr, lr, lg);          // K -> scr (Q dead after hoist)
  f16x8 aK[4];
#pragma unroll
  for (int mt = 0; mt < 4; ++mt) aK[mt] = ldS64(scr, mt * 16 + lr, lg);
  // aK round trip folds into the compiler's lgkmcnt(0) drain before BAR2.
  __syncthreads();  // BAR2: all stage reads done

  // ---- Xv regs -> S_XK ----
#pragma unroll
  for (int i = 0; i < 8; ++i) {
    int f = tid + (i << 8);
    *reinterpret_cast<f16x4*>(smem + S_XK + swzA(f >> 5, (f & 31) << 3)) = pfh[i];
  }

  // ---- S^T = K Q^T + scale/pos, softmax per q-col, attn out, P16 pack ----
  const float scale = exp2f(fminf(lsc[w], LOGIT_MAX_C) * L2E);
  const float* pos = pos_in + (((size_t)b * 4 + w) << 12);
  float* attn_out = d_attn + (((size_t)win * 4 + w) << 12);
  f16x4 P16[4][4];   // P16[mt][nt]: q=nt*16+lr, k=mt*16+lg*4+r
#pragma unroll
  for (int nt = 0; nt < 4; ++nt) {
    f32x4 s[4];
#pragma unroll
    for (int mt = 0; mt < 4; ++mt) s[mt] = f32x4{0.f, 0.f, 0.f, 0.f};
#pragma unroll
    for (int mt = 0; mt < 4; ++mt)
      s[mt] = __builtin_amdgcn_mfma_f32_16x16x32_f16(aK[mt], bQ[nt], s[mt], 0, 0, 0);
    const int q = nt * 16 + lr;   // lane's q-col; k = mt*16+lg*4+r (lane-local)
#pragma unroll
    for (int mt = 0; mt < 4; ++mt) {
      float4 pv = *reinterpret_cast<const float4*>(pos + (q << 6) + mt * 16 + lg * 4);
      s[mt][0] = s[mt][0] * scale + pv.x;
      s[mt][1] = s[mt][1] * scale + pv.y;
      s[mt][2] = s[mt][2] * scale + pv.z;
      s[mt][3] = s[mt][3] * scale + pv.w;
    }
    float m = s[0][0];
#pragma unroll
    for (int mt = 0; mt < 4; ++mt)
#pragma unroll
      for (int r = 0; r < 4; ++r) m = fmaxf(m, s[mt][r]);
    m = fmaxf(m, __shfl_xor(m, 16));
    m = fmaxf(m, __shfl_xor(m, 32));
    float sum = 0.f;
#pragma unroll
    for (int mt = 0; mt < 4; ++mt)
#pragma unroll
      for (int r = 0; r < 4; ++r) {
        float e = exp2f((s[mt][r] - m) * L2E);
        s[mt][r] = e;
        sum += e;
      }
    sum += __shfl_xor(sum, 16);
    sum += __shfl_xor(sum, 32);
    float rinv = __builtin_amdgcn_rcpf(sum);
#pragma unroll
    for (int mt = 0; mt < 4; ++mt) {
      float4 o;
      o.x = (s[mt][0] *= rinv);
      o.y = (s[mt][1] *= rinv);
      o.z = (s[mt][2] *= rinv);
      o.w = (s[mt][3] *= rinv);
      *reinterpret_cast<float4*>(attn_out + (q << 6) + mt * 16 + lg * 4) = o;
      P16[mt][nt][0] = (f16)s[mt][0];
      P16[mt][nt][1] = (f16)s[mt][1];
      P16[mt][nt][2] = (f16)s[mt][2];
      P16[mt][nt][3] = (f16)s[mt][3];
    }
  }

  // ---- P: h0 -> scr, h1 -> Ph1 (dead S_XQ chunk) — ONE exposed round trip ----
#define WR_P(MT, BASE)                                                             \
  {                                                                                \
    _Pragma("unroll") for (int nt = 0; nt < 4; ++nt) {                             \
      const int q = nt * 16 + lr;                                                  \
      *reinterpret_cast<f16x4*>((BASE) + (q << 6) +                                \
          (((((MT) & 1) << 5) + (lg << 3)) ^ (((q >> 1) & 3) << 4))) =             \
          P16[MT][nt];                                                             \
    }                                                                              \
  }
  WR_P(0, scr) WR_P(1, scr)
  WR_P(2, Ph1) WR_P(3, Ph1)
  f16x8 aP[4][2];
#pragma unroll
  for (int mt = 0; mt < 4; ++mt) {
    const int q = mt * 16 + lr;
    const int off = (q << 6) + ((lg << 4) ^ (((q >> 1) & 3) << 4));
    aP[mt][0] = *reinterpret_cast<const f16x8*>(scr + off);
    aP[mt][1] = *reinterpret_cast<const f16x8*>(Ph1 + off);
  }
#undef WR_P
  __syncthreads();  // BAR3: Xv staged; all P reads done (Ph1 chunks now dead)

  // ---- V projection (reads S_XK = Xv) -> V^T scr [32][64] (P h0 dead) -> bV ----
  proj_acc(smem + S_XK, Wv16, acc, w, lr, lg);
  {
    float c0 = bv[w * 32 + lr], c1 = bv[w * 32 + 16 + lr];
#pragma unroll
    for (int mt = 0; mt < 4; ++mt)
#pragma unroll
      for (int n = 0; n < 2; ++n) {
        int d = n * 16 + lr;                 // local feature row of V^T [32][64]
        f16x4 h;
        h[0] = (f16)(acc[mt][n][0] + (n ? c1 : c0));
        h[1] = (f16)(acc[mt][n][1] + (n ? c1 : c0));
        h[2] = (f16)(acc[mt][n][2] + (n ? c1 : c0));
        h[3] = (f16)(acc[mt][n][3] + (n ? c1 : c0));
        *reinterpret_cast<f16x4*>(scr + (d << 7) +
            ((mt * 32 + lg * 8) ^ ((d & 7) << 4))) = h;
      }
  }
  f16x8 bV[2][2];
#pragma unroll
  for (int n = 0; n < 2; ++n)
#pragma unroll
    for (int kt = 0; kt < 2; ++kt) {
      int d = n * 16 + lr;
      bV[n][kt] = *reinterpret_cast<const f16x8*>(scr + (d << 7) +
          ((kt * 64 + lg * 16) ^ ((d & 7) << 4)));
    }

  // ---- O_h = P @ V_h ----
  f32x4 oacc[4][2];
#pragma unroll
  for (int mt = 0; mt < 4; ++mt)
#pragma unroll
    for (int n = 0; n < 2; ++n)
      oacc[mt][n] = f32x4{0.f, 0.f, 0.f, 0.f};
#pragma unroll
  for (int mt = 0; mt < 4; ++mt)
#pragma unroll
    for (int kt = 0; kt < 2; ++kt) {
      oacc[mt][0] = __builtin_amdgcn_mfma_f32_16x16x32_f16(aP[mt][kt], bV[0][kt], oacc[mt][0], 0, 0, 0);
      oacc[mt][1] = __builtin_amdgcn_mfma_f32_16x16x32_f16(aP[mt][kt], bV[1][kt], oacc[mt][1], 0, 0, 0);
    }

  // ---- O (merged heads) -> S_XQ own cols (post-BAR3: P chunks all consumed) ----
  epi_rowmajor(oacc, smem + S_XQ, w, lr, lg);
  __syncthreads();  // BAR4: all O cols written

  // ---- x = O @ Wp^T + bp -> global fp32 ----
  f32x4 xacc[4][2];
  proj_acc(smem + S_XQ, Wp16, xacc, w, lr, lg);
  const float b0 = bp[w * 32 + lr];
  const float b1 = bp[w * 32 + 16 + lr];
  float* xo = d_x + winOff;
#pragma unroll
  for (int mt = 0; mt < 4; ++mt)
#pragma unroll
    for (int n = 0; n < 2; ++n)
#pragma unroll
      for (int r = 0; r < 4; ++r) {
        int row = mt * 16 + lg * 4 + r;
        int col = w * 32 + n * 16 + lr;
        xo[(row << 7) + col] = xacc[mt][n][r] + (n ? b1 : b0);
      }
}

extern "C" void kernel_launch(void* const* d_in, const int* in_sizes, int n_in,
                              void* d_out, int out_size, void* d_ws, size_t ws_size,
                              hipStream_t stream) {
  const float* q   = (const float*)d_in[0];
  const float* k   = (const float*)d_in[1];
  const float* v   = (const float*)d_in[2];
  const float* pos = (const float*)d_in[3];
  const float* Wq  = (const float*)d_in[4];
  const float* bq  = (const float*)d_in[5];
  const float* Wk  = (const float*)d_in[6];
  const float* Wv  = (const float*)d_in[7];
  const float* bv  = (const float*)d_in[8];
  const float* Wp  = (const float*)d_in[9];
  const float* bp  = (const float*)d_in[10];
  const float* ls  = (const float*)d_in[11];
  f16* W16 = (f16*)d_ws;   // 4 x 128 x 128 f16 = 128KB
  float* d_x    = (float*)d_out;
  float* d_attn = d_x + (size_t)16 * 16 * 16 * 64 * 128;  // 33,554,432
  wcvt_kernel<<<64, 256, 0, stream>>>(Wq, Wk, Wv, Wp, W16);
  fpca_kernel<<<4096, 256, 0, stream>>>(q, k, v, pos, W16, bq, bv, bp, ls,
                                        d_x, d_attn);
}